// Round 2
// baseline (709.842 us; speedup 1.0000x reference)
//
#include <hip/hip_runtime.h>

typedef unsigned short ushort_t;
typedef unsigned int uint_t;
typedef __attribute__((ext_vector_type(8))) short bf16x8;
typedef __attribute__((ext_vector_type(4))) float f32x4;

#define MFMA(a, b, c) __builtin_amdgcn_mfma_f32_16x16x32_bf16(a, b, c, 0, 0, 0)

static constexpr int BATCH = 16;
static constexpr int SEQ   = 4096;   // H*W
static constexpr int CH    = 128;
static constexpr int NGRP  = 32;
static constexpr float EPS = 1e-6f;
static constexpr float SCALE = 0.08838834764831845f; // 1/sqrt(128)

__device__ inline float bf2f(uint_t u) { return __uint_as_float(u << 16); }
__device__ inline ushort_t f2bf(float f) {
    uint_t u = __float_as_uint(f);
    u = (u + 0x7fff + ((u >> 16) & 1)) >> 16;
    return (ushort_t)u;
}

// ---------------- GroupNorm stats (fp32 input) ----------------
// grid 128 = batch(16) x chunk(8); block 256
__global__ void gn_partial(const float* __restrict__ x, float* __restrict__ stats) {
    int bid = blockIdx.x;
    int b = bid >> 3, chunk = bid & 7;
    int t = threadIdx.x;
    int c4 = (t & 31) * 4;   // one group = 4 channels
    int rowoff = t >> 5;     // 0..7
    const float* xb = x + (size_t)b * SEQ * CH;
    float s1 = 0.f, s2 = 0.f;
    int base_row = chunk * 512;
    for (int i = 0; i < 64; ++i) {
        int r = base_row + i * 8 + rowoff;
        float4 v = *(const float4*)(xb + (size_t)r * CH + c4);
        s1 += v.x + v.y + v.z + v.w;
        s2 += v.x * v.x + v.y * v.y + v.z * v.z + v.w * v.w;
    }
    __shared__ float red[256][2];
    red[t][0] = s1; red[t][1] = s2;
    __syncthreads();
    if (t < 32) {
        float a1 = 0.f, a2 = 0.f;
        for (int ro = 0; ro < 8; ++ro) {
            a1 += red[ro * 32 + t][0];
            a2 += red[ro * 32 + t][1];
        }
        atomicAdd(&stats[(b * NGRP + t) * 2 + 0], a1);
        atomicAdd(&stats[(b * NGRP + t) * 2 + 1], a2);
    }
}

__global__ void gn_finalize(float* __restrict__ stats) {
    int gi = threadIdx.x;  // 0..511
    float n = 16384.f;     // SEQ * 4 channels
    float sum = stats[gi * 2 + 0];
    float sq  = stats[gi * 2 + 1];
    float mean = sum / n;
    float var  = sq / n - mean * mean;
    stats[gi * 2 + 0] = mean;
    stats[gi * 2 + 1] = __frsqrt_rn(var + EPS);
}

// ---------------- normalize: h = (x-mean)*invstd*scale + bias -> bf16 ----------------
// 1048576 threads, 8 elems each
__global__ void normalize_h(const float* __restrict__ x, const float* __restrict__ stats,
                            const float* __restrict__ gsc, const float* __restrict__ gbi,
                            ushort_t* __restrict__ h) {
    size_t gid = (size_t)blockIdx.x * 256 + threadIdx.x;
    size_t e8 = gid * 8;
    int row = (int)(e8 >> 7);
    int c0  = (int)(e8 & 127);
    int b = row >> 12;
    int g0 = c0 >> 2;
    float2 st0 = ((const float2*)stats)[b * NGRP + g0];
    float2 st1 = ((const float2*)stats)[b * NGRP + g0 + 1];
    float4 x0 = *(const float4*)(x + e8);
    float4 x1 = *(const float4*)(x + e8 + 4);
    float4 s0 = *(const float4*)(gsc + c0);
    float4 s1 = *(const float4*)(gsc + c0 + 4);
    float4 b0 = *(const float4*)(gbi + c0);
    float4 b1 = *(const float4*)(gbi + c0 + 4);
    ushort_t outw[8];
    outw[0] = f2bf((x0.x - st0.x) * st0.y * s0.x + b0.x);
    outw[1] = f2bf((x0.y - st0.x) * st0.y * s0.y + b0.y);
    outw[2] = f2bf((x0.z - st0.x) * st0.y * s0.z + b0.z);
    outw[3] = f2bf((x0.w - st0.x) * st0.y * s0.w + b0.w);
    outw[4] = f2bf((x1.x - st1.x) * st1.y * s1.x + b1.x);
    outw[5] = f2bf((x1.y - st1.x) * st1.y * s1.y + b1.y);
    outw[6] = f2bf((x1.z - st1.x) * st1.y * s1.z + b1.z);
    outw[7] = f2bf((x1.w - st1.x) * st1.y * s1.w + b1.w);
    *(uint4*)(h + e8) = *(const uint4*)outw;
}

// ---------------- GEMM: out[M,128] = A_bf16[M,128] @ W_f32[128,128] + bias (+resid) ----------------
// grid.x = 512 (128-row M tiles); block 256 (4 waves)
template <bool OUT_F32, bool HAS_RESID>
__global__ __launch_bounds__(256) void gemm_nin(const ushort_t* __restrict__ A,
                                                const float* __restrict__ W,
                                                const float* __restrict__ bias,
                                                const float* __restrict__ resid,
                                                void* __restrict__ out) {
    __shared__ ushort_t lds_a[128][72];  // 128 rows x 64 k, pad 8
    __shared__ ushort_t lds_w[128][72];  // transposed: [n][k_local]
    int t = threadIdx.x;
    int wv = t >> 6, lane = t & 63, quad = lane >> 4, l16 = lane & 15;
    size_t m0 = (size_t)blockIdx.x * 128;
    f32x4 acc[2][8] = {};
    for (int kh = 0; kh < 2; ++kh) {
        int k0 = kh * 64;
        __syncthreads();
        // stage A half-tile (128x64), bf16
        for (int i = 0; i < 4; ++i) {
            int idx = (t + i * 256) * 8;
            int r = idx >> 6, c = idx & 63;
            *(uint4*)&lds_a[r][c] = *(const uint4*)(A + (m0 + r) * CH + k0 + c);
        }
        // stage W^T (fp32 k rows k0..k0+63 -> bf16 lds_w[n][k])
        for (int i = 0; i < 8; ++i) {
            int idx = (t + i * 256) * 4;     // flat = kl*128 + n
            int kl = idx >> 7, n = idx & 127;
            float4 wf = *(const float4*)(W + (size_t)(k0 + kl) * CH + n);
            lds_w[n + 0][kl] = f2bf(wf.x);
            lds_w[n + 1][kl] = f2bf(wf.y);
            lds_w[n + 2][kl] = f2bf(wf.z);
            lds_w[n + 3][kl] = f2bf(wf.w);
        }
        __syncthreads();
        for (int ks = 0; ks < 2; ++ks) {
            bf16x8 afrag[2];
            for (int tr = 0; tr < 2; ++tr)
                afrag[tr] = *(const bf16x8*)&lds_a[wv * 32 + tr * 16 + l16][ks * 32 + quad * 8];
            for (int tc = 0; tc < 8; ++tc) {
                bf16x8 bfrag = *(const bf16x8*)&lds_w[tc * 16 + l16][ks * 32 + quad * 8];
                for (int tr = 0; tr < 2; ++tr)
                    acc[tr][tc] = MFMA(afrag[tr], bfrag, acc[tr][tc]);
            }
        }
    }
    for (int tc = 0; tc < 8; ++tc) {
        int col = tc * 16 + l16;
        float bval = bias[col];
        for (int tr = 0; tr < 2; ++tr) {
            int rl = wv * 32 + tr * 16 + quad * 4;
            for (int r = 0; r < 4; ++r) {
                size_t row = m0 + rl + r;
                float v = acc[tr][tc][r] + bval;
                if (HAS_RESID) v += resid[row * CH + col];
                if (OUT_F32) ((float*)out)[row * CH + col] = v;
                else ((ushort_t*)out)[row * CH + col] = f2bf(v);
            }
        }
    }
}

// ---------------- flash attention (all-bf16 operands, fp32 accum) ----------------
// grid 512: b = bid & 15 (XCD-pinned), qtile = bid >> 4; block 256 (4 waves, 32 q-rows each)
__global__ __launch_bounds__(256) void flash_attn(const ushort_t* __restrict__ q,
                                                  const ushort_t* __restrict__ k,
                                                  const ushort_t* __restrict__ v,
                                                  ushort_t* __restrict__ o) {
    int bid = blockIdx.x;
    int b = bid & 15, qt = bid >> 4;
    int t = threadIdx.x;
    int wv = t >> 6, lane = t & 63, quad = lane >> 4, l16 = lane & 15;
    const size_t SB = (size_t)SEQ * CH;
    const ushort_t* qb = q + (size_t)b * SB;
    const ushort_t* kb = k + (size_t)b * SB;
    const ushort_t* vb = v + (size_t)b * SB;

    __shared__ ushort_t lds_k[64][136];      // [key][d], pad 8
    __shared__ ushort_t lds_vt[128][72];     // [d][key], pad 8
    __shared__ ushort_t lds_p[4][32][72];    // per-wave P, [qrow][key], pad 8

    // Q fragments held in registers for the whole kernel
    bf16x8 qfrag[2][4];
    int qrow_base = qt * 128 + wv * 32;
    for (int tr = 0; tr < 2; ++tr)
        for (int ks = 0; ks < 4; ++ks)
            qfrag[tr][ks] = *(const bf16x8*)(qb + (size_t)(qrow_base + tr * 16 + l16) * CH + ks * 32 + quad * 8);

    f32x4 oacc[2][8] = {};
    float m_r[2][4], l_r[2][4];
    for (int tr = 0; tr < 2; ++tr)
        for (int r = 0; r < 4; ++r) { m_r[tr][r] = -1e30f; l_r[tr][r] = 0.f; }

    for (int it = 0; it < 64; ++it) {
        int key0 = it * 64;
        __syncthreads();
        // stage K (64x128) row-major
        for (int i = 0; i < 4; ++i) {
            int idx = (t + i * 256) * 8;
            int r = idx >> 7, c = idx & 127;
            *(uint4*)&lds_k[r][c] = *(const uint4*)(kb + (size_t)(key0 + r) * CH + c);
        }
        // stage V transposed: lds_vt[d][key]
        for (int i = 0; i < 4; ++i) {
            int idx = (t + i * 256) * 8;
            int r = idx >> 7, c = idx & 127;
            uint4 vv = *(const uint4*)(vb + (size_t)(key0 + r) * CH + c);
            const ushort_t* pv = (const ushort_t*)&vv;
            for (int j = 0; j < 8; ++j) lds_vt[c + j][r] = pv[j];
        }
        __syncthreads();
        // S = Q K^T (per wave: 32 x 64)
        f32x4 s[2][4] = {};
        for (int ks = 0; ks < 4; ++ks) {
            bf16x8 kf[4];
            for (int tc = 0; tc < 4; ++tc)
                kf[tc] = *(const bf16x8*)&lds_k[tc * 16 + l16][ks * 32 + quad * 8];
            for (int tr = 0; tr < 2; ++tr)
                for (int tc = 0; tc < 4; ++tc)
                    s[tr][tc] = MFMA(qfrag[tr][ks], kf[tc], s[tr][tc]);
        }
        // online softmax per q-row
        for (int tr = 0; tr < 2; ++tr) {
            for (int r = 0; r < 4; ++r) {
                float sv[4];
                float mt = -1e30f;
                for (int tc = 0; tc < 4; ++tc) {
                    sv[tc] = s[tr][tc][r] * SCALE;
                    mt = fmaxf(mt, sv[tc]);
                }
                for (int off = 1; off < 16; off <<= 1)
                    mt = fmaxf(mt, __shfl_xor(mt, off, 64));
                float mnew = fmaxf(m_r[tr][r], mt);
                float alpha = __expf(m_r[tr][r] - mnew);
                float psum = 0.f;
                ushort_t pb[4];
                for (int tc = 0; tc < 4; ++tc) {
                    float p = __expf(sv[tc] - mnew);
                    psum += p;
                    pb[tc] = f2bf(p);
                }
                for (int off = 1; off < 16; off <<= 1)
                    psum += __shfl_xor(psum, off, 64);
                m_r[tr][r] = mnew;
                l_r[tr][r] = l_r[tr][r] * alpha + psum;
                for (int tc8 = 0; tc8 < 8; ++tc8) oacc[tr][tc8][r] *= alpha;
                int prow = tr * 16 + quad * 4 + r;
                for (int tc = 0; tc < 4; ++tc)
                    lds_p[wv][prow][tc * 16 + l16] = pb[tc];
            }
        }
        __syncthreads();
        // O += P @ V
        for (int ks = 0; ks < 2; ++ks) {
            bf16x8 pf[2];
            for (int tr = 0; tr < 2; ++tr)
                pf[tr] = *(const bf16x8*)&lds_p[wv][tr * 16 + l16][ks * 32 + quad * 8];
            for (int tc = 0; tc < 8; ++tc) {
                bf16x8 vf = *(const bf16x8*)&lds_vt[tc * 16 + l16][ks * 32 + quad * 8];
                for (int tr = 0; tr < 2; ++tr)
                    oacc[tr][tc] = MFMA(pf[tr], vf, oacc[tr][tc]);
            }
        }
    }
    // epilogue: O / l -> bf16
    size_t orow_base = (size_t)b * SEQ + qt * 128 + wv * 32;
    for (int tc = 0; tc < 8; ++tc) {
        int col = tc * 16 + l16;
        for (int tr = 0; tr < 2; ++tr) {
            float inv0 = 1.f / l_r[tr][0], inv1 = 1.f / l_r[tr][1];
            float inv2 = 1.f / l_r[tr][2], inv3 = 1.f / l_r[tr][3];
            size_t rbase = orow_base + tr * 16 + quad * 4;
            o[(rbase + 0) * CH + col] = f2bf(oacc[tr][tc][0] * inv0);
            o[(rbase + 1) * CH + col] = f2bf(oacc[tr][tc][1] * inv1);
            o[(rbase + 2) * CH + col] = f2bf(oacc[tr][tc][2] * inv2);
            o[(rbase + 3) * CH + col] = f2bf(oacc[tr][tc][3] * inv3);
        }
    }
}

extern "C" void kernel_launch(void* const* d_in, const int* in_sizes, int n_in,
                              void* d_out, int out_size, void* d_ws, size_t ws_size,
                              hipStream_t stream) {
    const float* x   = (const float*)d_in[0];
    const float* gsc = (const float*)d_in[1];
    const float* gbi = (const float*)d_in[2];
    const float* wq  = (const float*)d_in[3];
    const float* bq  = (const float*)d_in[4];
    const float* wk  = (const float*)d_in[5];
    const float* bk  = (const float*)d_in[6];
    const float* wvp = (const float*)d_in[7];
    const float* bv  = (const float*)d_in[8];
    const float* wo  = (const float*)d_in[9];
    const float* bo  = (const float*)d_in[10];
    float* outp = (float*)d_out;

    const size_t NELEM = (size_t)BATCH * SEQ * CH;  // 8388608
    float*    stats = (float*)d_ws;
    ushort_t* hbuf  = (ushort_t*)((char*)d_ws + 4096);
    ushort_t* qbuf  = hbuf + NELEM;
    ushort_t* kbuf  = qbuf + NELEM;
    ushort_t* vbuf  = kbuf + NELEM;
    ushort_t* abuf  = hbuf;  // reuse h after QKV are built

    hipMemsetAsync(stats, 0, BATCH * NGRP * 2 * sizeof(float), stream);
    gn_partial<<<128, 256, 0, stream>>>(x, stats);
    gn_finalize<<<1, BATCH * NGRP, 0, stream>>>(stats);
    normalize_h<<<(int)(NELEM / 8 / 256), 256, 0, stream>>>(x, stats, gsc, gbi, hbuf);
    gemm_nin<false, false><<<512, 256, 0, stream>>>(hbuf, wq, bq, nullptr, qbuf);
    gemm_nin<false, false><<<512, 256, 0, stream>>>(hbuf, wk, bk, nullptr, kbuf);
    gemm_nin<false, false><<<512, 256, 0, stream>>>(hbuf, wvp, bv, nullptr, vbuf);
    flash_attn<<<512, 256, 0, stream>>>(qbuf, kbuf, vbuf, abuf);
    gemm_nin<true, true><<<512, 256, 0, stream>>>(abuf, wo, bo, x, outp);
}

// Round 3
// 493.910 us; speedup vs baseline: 1.4372x; 1.4372x over previous
//
#include <hip/hip_runtime.h>
#include <hip/hip_bf16.h>

typedef unsigned short ushort_t;
typedef unsigned int uint_t;
typedef __attribute__((ext_vector_type(8))) short bf16x8;
typedef __attribute__((ext_vector_type(4))) short bf16x4;
typedef __attribute__((ext_vector_type(4))) float f32x4;

#define MFMA32(a, b, c) __builtin_amdgcn_mfma_f32_16x16x32_bf16(a, b, c, 0, 0, 0)

#if __has_builtin(__builtin_amdgcn_mfma_f32_16x16x16bf16_1k)
#define MFMA16(a, b, c) __builtin_amdgcn_mfma_f32_16x16x16bf16_1k(a, b, c, 0, 0, 0)
#else
static __device__ inline f32x4 mfma16_asm(bf16x4 a, bf16x4 b, f32x4 c) {
    asm("v_mfma_f32_16x16x16_bf16 %0, %1, %2, %0\n\ts_nop 3"
        : "+v"(c) : "v"(a), "v"(b));
    return c;
}
#define MFMA16(a, b, c) mfma16_asm(a, b, c)
#endif

static constexpr int BATCH = 16;
static constexpr int SEQ   = 4096;   // H*W
static constexpr int CH    = 128;
static constexpr int NGRP  = 32;
static constexpr float EPS = 1e-6f;
// softmax scale folded into exp2 domain: 1/sqrt(128) * log2(e)
static constexpr float C2 = 0.08838834764831845f * 1.4426950408889634f;

__device__ inline ushort_t f2bf(float f) {
    uint_t u = __float_as_uint(f);
    u = (u + 0x7fff + ((u >> 16) & 1)) >> 16;
    return (ushort_t)u;
}

// ---------------- GroupNorm stats (fp32 input) ----------------
__global__ void gn_partial(const float* __restrict__ x, float* __restrict__ stats) {
    int bid = blockIdx.x;
    int b = bid >> 3, chunk = bid & 7;
    int t = threadIdx.x;
    int c4 = (t & 31) * 4;   // one group = 4 channels
    int rowoff = t >> 5;     // 0..7
    const float* xb = x + (size_t)b * SEQ * CH;
    float s1 = 0.f, s2 = 0.f;
    int base_row = chunk * 512;
    for (int i = 0; i < 64; ++i) {
        int r = base_row + i * 8 + rowoff;
        float4 v = *(const float4*)(xb + (size_t)r * CH + c4);
        s1 += v.x + v.y + v.z + v.w;
        s2 += v.x * v.x + v.y * v.y + v.z * v.z + v.w * v.w;
    }
    __shared__ float red[256][2];
    red[t][0] = s1; red[t][1] = s2;
    __syncthreads();
    if (t < 32) {
        float a1 = 0.f, a2 = 0.f;
        for (int ro = 0; ro < 8; ++ro) {
            a1 += red[ro * 32 + t][0];
            a2 += red[ro * 32 + t][1];
        }
        atomicAdd(&stats[(b * NGRP + t) * 2 + 0], a1);
        atomicAdd(&stats[(b * NGRP + t) * 2 + 1], a2);
    }
}

__global__ void gn_finalize(float* __restrict__ stats) {
    int gi = threadIdx.x;  // 0..511
    float n = 16384.f;     // SEQ * 4 channels
    float sum = stats[gi * 2 + 0];
    float sq  = stats[gi * 2 + 1];
    float mean = sum / n;
    float var  = sq / n - mean * mean;
    stats[gi * 2 + 0] = mean;
    stats[gi * 2 + 1] = __frsqrt_rn(var + EPS);
}

// ---------------- normalize: h = (x-mean)*invstd*scale + bias -> bf16 ----------------
__global__ void normalize_h(const float* __restrict__ x, const float* __restrict__ stats,
                            const float* __restrict__ gsc, const float* __restrict__ gbi,
                            ushort_t* __restrict__ h) {
    size_t gid = (size_t)blockIdx.x * 256 + threadIdx.x;
    size_t e8 = gid * 8;
    int row = (int)(e8 >> 7);
    int c0  = (int)(e8 & 127);
    int b = row >> 12;
    int g0 = c0 >> 2;
    float2 st0 = ((const float2*)stats)[b * NGRP + g0];
    float2 st1 = ((const float2*)stats)[b * NGRP + g0 + 1];
    float4 x0 = *(const float4*)(x + e8);
    float4 x1 = *(const float4*)(x + e8 + 4);
    float4 s0 = *(const float4*)(gsc + c0);
    float4 s1 = *(const float4*)(gsc + c0 + 4);
    float4 b0 = *(const float4*)(gbi + c0);
    float4 b1 = *(const float4*)(gbi + c0 + 4);
    ushort_t outw[8];
    outw[0] = f2bf((x0.x - st0.x) * st0.y * s0.x + b0.x);
    outw[1] = f2bf((x0.y - st0.x) * st0.y * s0.y + b0.y);
    outw[2] = f2bf((x0.z - st0.x) * st0.y * s0.z + b0.z);
    outw[3] = f2bf((x0.w - st0.x) * st0.y * s0.w + b0.w);
    outw[4] = f2bf((x1.x - st1.x) * st1.y * s1.x + b1.x);
    outw[5] = f2bf((x1.y - st1.x) * st1.y * s1.y + b1.y);
    outw[6] = f2bf((x1.z - st1.x) * st1.y * s1.z + b1.z);
    outw[7] = f2bf((x1.w - st1.x) * st1.y * s1.w + b1.w);
    *(uint4*)(h + e8) = *(const uint4*)outw;
}

// ---------------- fused QKV GEMM ----------------
// out q,k row-major [b*seq][128]; v written TRANSPOSED: vt[b][d][seq]
// grid 512 (128-row tiles), block 256
__global__ __launch_bounds__(256) void gemm_qkv(const ushort_t* __restrict__ A,
                                                const float* __restrict__ Wq,
                                                const float* __restrict__ Wk,
                                                const float* __restrict__ Wv,
                                                const float* __restrict__ Bq,
                                                const float* __restrict__ Bk,
                                                const float* __restrict__ Bv,
                                                ushort_t* __restrict__ outq,
                                                ushort_t* __restrict__ outk,
                                                ushort_t* __restrict__ outvt) {
    __shared__ ushort_t lds_a[128][136];  // full 128x128 A tile (bf16)
    __shared__ ushort_t lds_w[128][72];   // W^T half-tile [n][k_local]
    int t = threadIdx.x;
    int wv = t >> 6, lane = t & 63, quad = lane >> 4, l16 = lane & 15;
    size_t m0 = (size_t)blockIdx.x * 128;
    // stage A once
    for (int i = 0; i < 8; ++i) {
        int idx = (t + i * 256) * 8;
        int r = idx >> 7, c = idx & 127;
        *(uint4*)&lds_a[r][c] = *(const uint4*)(A + (m0 + r) * CH + c);
    }
    int batch = (int)(m0 >> 12);
    int seq0  = (int)(m0 & 4095);
    for (int j = 0; j < 3; ++j) {
        const float* W  = (j == 0) ? Wq : (j == 1) ? Wk : Wv;
        const float* Bi = (j == 0) ? Bq : (j == 1) ? Bk : Bv;
        f32x4 acc[2][8] = {};
        for (int kh = 0; kh < 2; ++kh) {
            int k0 = kh * 64;
            __syncthreads();   // protect lds_w reuse (also orders A staging before first read)
            for (int i = 0; i < 8; ++i) {
                int idx = (t + i * 256) * 4;     // flat = kl*128 + n
                int kl = idx >> 7, n = idx & 127;
                float4 wf = *(const float4*)(W + (size_t)(k0 + kl) * CH + n);
                lds_w[n + 0][kl] = f2bf(wf.x);
                lds_w[n + 1][kl] = f2bf(wf.y);
                lds_w[n + 2][kl] = f2bf(wf.z);
                lds_w[n + 3][kl] = f2bf(wf.w);
            }
            __syncthreads();
            for (int ks = 0; ks < 2; ++ks) {
                bf16x8 afrag[2];
                for (int tr = 0; tr < 2; ++tr)
                    afrag[tr] = *(const bf16x8*)&lds_a[wv * 32 + tr * 16 + l16][k0 + ks * 32 + quad * 8];
                for (int tc = 0; tc < 8; ++tc) {
                    bf16x8 bfrag = *(const bf16x8*)&lds_w[tc * 16 + l16][ks * 32 + quad * 8];
                    for (int tr = 0; tr < 2; ++tr)
                        acc[tr][tc] = MFMA32(afrag[tr], bfrag, acc[tr][tc]);
                }
            }
        }
        // epilogue
        for (int tc = 0; tc < 8; ++tc) {
            int col = tc * 16 + l16;
            float bval = Bi[col];
            for (int tr = 0; tr < 2; ++tr) {
                int rl = wv * 32 + tr * 16 + quad * 4;
                for (int r = 0; r < 4; ++r) {
                    float vv = acc[tr][tc][r] + bval;
                    if (j == 2) {
                        // V^T: [b][d=col][seq]
                        outvt[(size_t)batch * CH * SEQ + (size_t)col * SEQ + seq0 + rl + r] = f2bf(vv);
                    } else {
                        ushort_t* op = (j == 0) ? outq : outk;
                        op[(m0 + rl + r) * CH + col] = f2bf(vv);
                    }
                }
            }
        }
    }
}

// ---------------- flash attention, S^T orientation ----------------
// S^T = K Q^T  (A=K tile, B=Q^T frag)  -> C layout: qrow=l16, key=quad*4+r
// P^T feeds PV directly as B-operand of 16x16x16 MFMA (k=quad*4+j matches!)
// O^T[d][qrow] += V^T[d][key] P^T[key][qrow]
// grid 512: b = bid & 15 (XCD-pinned), qtile = bid >> 4; block 256 (4 waves, 32 qrows each)
__global__ __launch_bounds__(256, 3) void flash_attn2(const ushort_t* __restrict__ q,
                                                      const ushort_t* __restrict__ k,
                                                      const ushort_t* __restrict__ vt,
                                                      ushort_t* __restrict__ o) {
    int bid = blockIdx.x;
    int b = bid & 15, qt = bid >> 4;
    int t = threadIdx.x;
    int wv = t >> 6, lane = t & 63, quad = lane >> 4, l16 = lane & 15;
    const size_t SB = (size_t)SEQ * CH;
    const ushort_t* qb  = q  + (size_t)b * SB;
    const ushort_t* kb  = k  + (size_t)b * SB;
    const ushort_t* vtb = vt + (size_t)b * SB;   // [d][seq]

    __shared__ ushort_t lds_k[64][136];    // [key][d]
    __shared__ ushort_t lds_vt[128][72];   // [d][key_local]

    int qrow_base = qt * 128 + wv * 32;
    // Q^T B-fragments (n=qrow=l16, k=d=quad*8+j) — contiguous 16B global loads
    bf16x8 qfrag[2][4];
    for (int nt = 0; nt < 2; ++nt)
        for (int ks = 0; ks < 4; ++ks)
            qfrag[nt][ks] = *(const bf16x8*)(qb + (size_t)(qrow_base + nt * 16 + l16) * CH + ks * 32 + quad * 8);

    f32x4 oacc[8][2] = {};    // [mt=d/16][nt]
    float m2[2] = {-1e30f, -1e30f};
    float lsum[2] = {0.f, 0.f};

    for (int it = 0; it < 64; ++it) {
        int key0 = it * 64;
        __syncthreads();
        // stage K tile (64 keys x 128 d), row-major, b128
        for (int i = 0; i < 4; ++i) {
            int idx = (t + i * 256) * 8;
            int r = idx >> 7, c = idx & 127;
            *(uint4*)&lds_k[r][c] = *(const uint4*)(kb + (size_t)(key0 + r) * CH + c);
        }
        // stage V^T tile (128 d x 64 keys) — already transposed in global, b128
        for (int i = 0; i < 4; ++i) {
            int idx = (t + i * 256) * 8;
            int d = idx >> 6, kl = idx & 63;
            *(uint4*)&lds_vt[d][kl] = *(const uint4*)(vtb + (size_t)d * SEQ + key0 + kl);
        }
        __syncthreads();

        // S^T = K·Q^T : per wave 64 keys x 32 qrows
        f32x4 s[4][2] = {};   // [kt][nt]
        for (int ks = 0; ks < 4; ++ks) {
            bf16x8 kf[4];
            for (int kt = 0; kt < 4; ++kt)
                kf[kt] = *(const bf16x8*)&lds_k[kt * 16 + l16][ks * 32 + quad * 8];
            for (int kt = 0; kt < 4; ++kt)
                for (int nt = 0; nt < 2; ++nt)
                    s[kt][nt] = MFMA32(kf[kt], qfrag[nt][ks], s[kt][nt]);
        }

        // online softmax (exp2 domain); rows live in-lane: only 2 shfls per reduce
        bf16x4 pk[4][2];
        for (int nt = 0; nt < 2; ++nt) {
            float mt_ = -1e30f;
            for (int kt = 0; kt < 4; ++kt)
                for (int r = 0; r < 4; ++r) {
                    s[kt][nt][r] *= C2;
                    mt_ = fmaxf(mt_, s[kt][nt][r]);
                }
            mt_ = fmaxf(mt_, __shfl_xor(mt_, 16, 64));
            mt_ = fmaxf(mt_, __shfl_xor(mt_, 32, 64));
            float mnew = fmaxf(m2[nt], mt_);
            float alpha = exp2f(m2[nt] - mnew);
            float ps = 0.f;
            for (int kt = 0; kt < 4; ++kt) {
                float p0 = exp2f(s[kt][nt][0] - mnew);
                float p1 = exp2f(s[kt][nt][1] - mnew);
                float p2 = exp2f(s[kt][nt][2] - mnew);
                float p3 = exp2f(s[kt][nt][3] - mnew);
                ps += (p0 + p1) + (p2 + p3);
                __hip_bfloat162 h01 = __float22bfloat162_rn(float2{p0, p1});
                __hip_bfloat162 h23 = __float22bfloat162_rn(float2{p2, p3});
                uint2 pu;
                __builtin_memcpy(&pu.x, &h01, 4);
                __builtin_memcpy(&pu.y, &h23, 4);
                __builtin_memcpy(&pk[kt][nt], &pu, 8);
            }
            ps += __shfl_xor(ps, 16, 64);
            ps += __shfl_xor(ps, 32, 64);
            m2[nt] = mnew;
            lsum[nt] = lsum[nt] * alpha + ps;
            for (int mt = 0; mt < 8; ++mt)
                for (int r = 0; r < 4; ++r)
                    oacc[mt][nt][r] *= alpha;
        }

        // O^T += V^T · P^T  (16x16x16, P^T straight from registers)
        for (int kt = 0; kt < 4; ++kt) {
            for (int mt = 0; mt < 8; ++mt) {
                bf16x4 vf = *(const bf16x4*)&lds_vt[mt * 16 + l16][kt * 16 + quad * 4];
                oacc[mt][0] = MFMA16(vf, pk[kt][0], oacc[mt][0]);
                oacc[mt][1] = MFMA16(vf, pk[kt][1], oacc[mt][1]);
            }
        }
    }

    // epilogue: O[qrow][d] = O^T / l   (scalar stores; L2 merges)
    float inv0 = 1.f / lsum[0], inv1 = 1.f / lsum[1];
    for (int mt = 0; mt < 8; ++mt) {
        for (int nt = 0; nt < 2; ++nt) {
            float inv = nt ? inv1 : inv0;
            size_t row = (size_t)b * SEQ + qrow_base + nt * 16 + l16;
            for (int r = 0; r < 4; ++r) {
                int d = mt * 16 + quad * 4 + r;
                o[row * CH + d] = f2bf(oacc[mt][nt][r] * inv);
            }
        }
    }
}

// ---------------- final GEMM: out = A_bf16 @ W + bias + resid (fp32 out) ----------------
__global__ __launch_bounds__(256) void gemm_out(const ushort_t* __restrict__ A,
                                                const float* __restrict__ W,
                                                const float* __restrict__ bias,
                                                const float* __restrict__ resid,
                                                float* __restrict__ out) {
    __shared__ ushort_t lds_a[128][72];
    __shared__ ushort_t lds_w[128][72];
    int t = threadIdx.x;
    int wv = t >> 6, lane = t & 63, quad = lane >> 4, l16 = lane & 15;
    size_t m0 = (size_t)blockIdx.x * 128;
    f32x4 acc[2][8] = {};
    for (int kh = 0; kh < 2; ++kh) {
        int k0 = kh * 64;
        __syncthreads();
        for (int i = 0; i < 4; ++i) {
            int idx = (t + i * 256) * 8;
            int r = idx >> 6, c = idx & 63;
            *(uint4*)&lds_a[r][c] = *(const uint4*)(A + (m0 + r) * CH + k0 + c);
        }
        for (int i = 0; i < 8; ++i) {
            int idx = (t + i * 256) * 4;
            int kl = idx >> 7, n = idx & 127;
            float4 wf = *(const float4*)(W + (size_t)(k0 + kl) * CH + n);
            lds_w[n + 0][kl] = f2bf(wf.x);
            lds_w[n + 1][kl] = f2bf(wf.y);
            lds_w[n + 2][kl] = f2bf(wf.z);
            lds_w[n + 3][kl] = f2bf(wf.w);
        }
        __syncthreads();
        for (int ks = 0; ks < 2; ++ks) {
            bf16x8 afrag[2];
            for (int tr = 0; tr < 2; ++tr)
                afrag[tr] = *(const bf16x8*)&lds_a[wv * 32 + tr * 16 + l16][ks * 32 + quad * 8];
            for (int tc = 0; tc < 8; ++tc) {
                bf16x8 bfrag = *(const bf16x8*)&lds_w[tc * 16 + l16][ks * 32 + quad * 8];
                for (int tr = 0; tr < 2; ++tr)
                    acc[tr][tc] = MFMA32(afrag[tr], bfrag, acc[tr][tc]);
            }
        }
    }
    for (int tc = 0; tc < 8; ++tc) {
        int col = tc * 16 + l16;
        float bval = bias[col];
        for (int tr = 0; tr < 2; ++tr) {
            int rl = wv * 32 + tr * 16 + quad * 4;
            for (int r = 0; r < 4; ++r) {
                size_t row = m0 + rl + r;
                out[row * CH + col] = acc[tr][tc][r] + bval + resid[row * CH + col];
            }
        }
    }
}

extern "C" void kernel_launch(void* const* d_in, const int* in_sizes, int n_in,
                              void* d_out, int out_size, void* d_ws, size_t ws_size,
                              hipStream_t stream) {
    const float* x   = (const float*)d_in[0];
    const float* gsc = (const float*)d_in[1];
    const float* gbi = (const float*)d_in[2];
    const float* wq  = (const float*)d_in[3];
    const float* bq  = (const float*)d_in[4];
    const float* wk  = (const float*)d_in[5];
    const float* bk  = (const float*)d_in[6];
    const float* wvp = (const float*)d_in[7];
    const float* bv  = (const float*)d_in[8];
    const float* wo  = (const float*)d_in[9];
    const float* bo  = (const float*)d_in[10];
    float* outp = (float*)d_out;

    const size_t NELEM = (size_t)BATCH * SEQ * CH;  // 8388608
    float*    stats = (float*)d_ws;
    ushort_t* hbuf  = (ushort_t*)((char*)d_ws + 4096);
    ushort_t* qbuf  = hbuf + NELEM;
    ushort_t* kbuf  = qbuf + NELEM;
    ushort_t* vtbuf = kbuf + NELEM;
    ushort_t* abuf  = hbuf;  // reuse h after QKV are built

    hipMemsetAsync(stats, 0, BATCH * NGRP * 2 * sizeof(float), stream);
    gn_partial<<<128, 256, 0, stream>>>(x, stats);
    gn_finalize<<<1, BATCH * NGRP, 0, stream>>>(stats);
    normalize_h<<<(int)(NELEM / 8 / 256), 256, 0, stream>>>(x, stats, gsc, gbi, hbuf);
    gemm_qkv<<<512, 256, 0, stream>>>(hbuf, wq, wk, wvp, bq, bk, bv, qbuf, kbuf, vtbuf);
    flash_attn2<<<512, 256, 0, stream>>>(qbuf, kbuf, vtbuf, abuf);
    gemm_out<<<512, 256, 0, stream>>>(abuf, wo, bo, x, outp);
}